// Round 14
// baseline (262.732 us; speedup 1.0000x reference)
//
#include <hip/hip_runtime.h>
#include <stdint.h>

#define MDIM 4096
#define KDIM 4096
#define NDIM 11008
#define KP   (KDIM/8)    // 512 packed int32 per N-row

typedef float  f32x4   __attribute__((ext_vector_type(4)));
typedef __bf16 bf16x8  __attribute__((ext_vector_type(8)));
typedef unsigned short u16x8 __attribute__((ext_vector_type(8)));
typedef int    i32x4   __attribute__((ext_vector_type(4)));
typedef int    i32x16  __attribute__((ext_vector_type(16)));
typedef char   c8x8    __attribute__((ext_vector_type(8)));
typedef char   c8x16   __attribute__((ext_vector_type(16)));

// RNE f32 -> bf16 bits (matches jax astype(bf16) for non-NaN inputs)
__device__ __forceinline__ unsigned short f2bf(float f) {
  uint32_t u = __builtin_bit_cast(uint32_t, f);
  u += 0x7FFFu + ((u >> 16) & 1u);
  return (unsigned short)(u >> 16);
}
__device__ __forceinline__ float bf2f(unsigned short h) {
  return __builtin_bit_cast(float, (uint32_t)h << 16);
}
__device__ __forceinline__ float bf16r(float f) { return bf2f(f2bf(f)); }

// async global -> LDS, 16B per lane, wave-uniform LDS base + lane*16
__device__ __forceinline__ void lds16(const void* g, void* l) {
  __builtin_amdgcn_global_load_lds(
      (const __attribute__((address_space(1))) unsigned int*)g,
      (__attribute__((address_space(3))) unsigned int*)l, 16, 0, 0);
}

// ---------------- pre-pass 1: unpack int4 words -> int8 Q8[N][K] ------------
__global__ __launch_bounds__(256) void repack_q_kernel(
    const uint32_t* __restrict__ wq, c8x8* __restrict__ Q8) {
  int idx = blockIdx.x * 256 + threadIdx.x;   // [0, N*KP)
  uint32_t w = wq[idx];
  c8x8 v;
#pragma unroll
  for (int j = 0; j < 8; ++j) v[j] = (char)((w >> (4 * j)) & 0xF);
  Q8[idx] = v;
}

// ---------------- pre-pass 2: x f32 -> per-row int8 + delta + exact bf16 sum
__global__ __launch_bounds__(256) void quant_x_kernel(
    const float* __restrict__ x, c8x16* __restrict__ X8,
    float* __restrict__ delta, float* __restrict__ xsum) {
  __shared__ float red[256];
  const int row = blockIdx.x, t = threadIdx.x;
  const float4* xr = (const float4*)(x + (size_t)row * KDIM);
  float xb[16];
#pragma unroll
  for (int i = 0; i < 4; ++i) {
    float4 f = xr[t * 4 + i];
    xb[i * 4 + 0] = bf16r(f.x); xb[i * 4 + 1] = bf16r(f.y);
    xb[i * 4 + 2] = bf16r(f.z); xb[i * 4 + 3] = bf16r(f.w);
  }
  float mx = 0.f, sm = 0.f;
#pragma unroll
  for (int j = 0; j < 16; ++j) { mx = fmaxf(mx, fabsf(xb[j])); sm += xb[j]; }
  red[t] = mx; __syncthreads();
  for (int o = 128; o > 0; o >>= 1) {
    if (t < o) red[t] = fmaxf(red[t], red[t + o]);
    __syncthreads();
  }
  const float rmx = red[0];
  __syncthreads();
  red[t] = sm; __syncthreads();
  for (int o = 128; o > 0; o >>= 1) {
    if (t < o) red[t] += red[t + o];
    __syncthreads();
  }
  const float rsm = red[0];
  const float inv = (rmx > 0.f) ? 127.0f / rmx : 0.f;
  if (t == 0) {
    delta[row] = (rmx > 0.f) ? rmx / 127.0f : 0.f;
    xsum[row]  = rsm;
  }
  c8x16 q;
#pragma unroll
  for (int j = 0; j < 16; ++j) q[j] = (char)__float2int_rn(xb[j] * inv);
  X8[(size_t)row * 256 + t] = q;
}

// ---------------- main GEMM: 256x256, 4 waves, i8 32x32x32, BARRIER-FREE ----
// Each wave is fully self-sufficient: it stages ITS OWN A-rows (wm*128..+128)
// and B-cols (wn*128..+128) into a private 32KB LDS region (2-slot ring of
// 16KB = A 8KB + B 8KB per 64B-K-half) and reads only that region. ZERO
// s_barrier in the kernel — sync is per-wave counted vmcnt only:
//   iter t: STAGE(t+1) -> VMWAIT(16) [retires exactly stage(t); stage(t+1)
//   stays in flight] -> READ/MFMA(t).
// WAR on slot recycle: STAGE(t+1) overwrites slot (t+1)&1, last read at
// iter t-1; those ds_reads completed (lgkm forced before iter t-1's MFMAs,
// which precede this STAGE in per-wave program order). Rationale: r3-r13 all
// plateau at 41-48% MfmaUtil under cross-wave barrier lockstep; with private
// staging each wave free-runs, reads overlap MFMAs, waves de-phase.
// Duplicated A/B fetch (2x per block) is L3-absorbed (X8+Q8 = 62MB resident).
// Subtile swizzle + read offsets verbatim r10/r13 (0-conflict measured);
// epilogue verbatim r13 (passing).
__global__ __launch_bounds__(256, 1) void gemm_i8_kernel(
    const char* __restrict__ A8, const char* __restrict__ Q8,
    const float* __restrict__ delta, const float* __restrict__ xsum,
    const float* __restrict__ scales, const float* __restrict__ zeros,
    const float* __restrict__ bias, float* __restrict__ out) {
  __shared__ __align__(16) char smem[131072];  // 4 waves x 32KB private

  const int tid  = threadIdx.x;
  const int lane = tid & 63;
  const int wave = tid >> 6;     // 0..3
  const int wm   = wave >> 1;    // 0..1 : M half (128 rows)
  const int wn   = wave & 1;     // 0..1 : N half (128 cols)

  // XCD-aware bijective swizzle: 688 = 8 * 86 blocks (verbatim).
  const int b   = blockIdx.x;
  const int swz = (b & 7) * 86 + (b >> 3);
  const int mt  = swz / 43;
  const int nt  = swz - mt * 43;
  const int bm0 = mt * 256, bn0 = nt * 256;

  // staging (r10 pattern): lane l writes subtile bytes [l*16,+16); stored
  // position schunk holds global chunk schunk ^ (b3(srow)<<1) ^ parity(j&1).
  const int srow   = lane >> 2;
  const int schunk = lane & 3;
  const int p0c    = schunk ^ (((srow >> 3) & 1) << 1);
  // wave-private operand rows/cols
  const char* aE = A8 + (size_t)(bm0 + wm * 128 + srow) * KDIM + (size_t)(p0c * 16);
  const char* aO = A8 + (size_t)(bm0 + wm * 128 + srow) * KDIM + (size_t)((p0c ^ 1) * 16);
  const char* bE = Q8 + (size_t)(bn0 + wn * 128 + srow) * KDIM + (size_t)(p0c * 16);
  const char* bO = Q8 + (size_t)(bn0 + wn * 128 + srow) * KDIM + (size_t)((p0c ^ 1) * 16);

  // fragment read offsets (r10-proven zero-conflict pattern)
  const int r31 = lane & 31;
  const int sub = r31 >> 4;
  const int r15 = r31 & 15;
  const int hk  = lane >> 5;
  const int rd0 = sub * 1024 + r15 * 64 + ((hk ^ sub) << 4) + ((r15 & 8) << 2);
  const int rd1 = rd0 ^ 32;

  const int wbase = wave << 15;   // 32KB private region

  i32x16 acc[4][4];
#pragma unroll
  for (int i = 0; i < 4; ++i)
#pragma unroll
    for (int j = 0; j < 4; ++j)
#pragma unroll
      for (int r = 0; r < 16; ++r) acc[i][j][r] = 0;

  i32x4 Af[4], Bf[4];

// stage this wave's A(8KB)+B(8KB) for K-half t into slot (16 lds16)
#define STAGE_AB(t, slot)                                                   \
  do {                                                                      \
    const size_t ko_ = (size_t)(t) * 64;                                    \
    char* da_ = smem + wbase + (slot) * 16384;                              \
    char* db_ = da_ + 8192;                                                 \
    _Pragma("unroll") for (int j = 0; j < 8; ++j) {                         \
      lds16(((j & 1) ? aO : aE) + (size_t)j * 16 * KDIM + ko_,              \
            da_ + j * 1024);                                                \
      lds16(((j & 1) ? bO : bE) + (size_t)j * 16 * KDIM + ko_,              \
            db_ + j * 1024);                                                \
    }                                                                       \
  } while (0)

#define READ8(slot, KS)                                                     \
  do {                                                                      \
    const int ro_ = (KS) ? rd1 : rd0;                                       \
    const int sb_ = wbase + (slot) * 16384;                                 \
    _Pragma("unroll") for (int mf = 0; mf < 4; ++mf)                        \
        Af[mf] = *(const i32x4*)(smem + sb_ + mf * 2048 + ro_);             \
    _Pragma("unroll") for (int nf = 0; nf < 4; ++nf)                        \
        Bf[nf] = *(const i32x4*)(smem + sb_ + 8192 + nf * 2048 + ro_);      \
  } while (0)

#define MFMA16()                                                            \
  __builtin_amdgcn_s_setprio(1);                                            \
  _Pragma("unroll") for (int mf = 0; mf < 4; ++mf)                          \
      _Pragma("unroll") for (int nf = 0; nf < 4; ++nf)                      \
          acc[mf][nf] = __builtin_amdgcn_mfma_i32_32x32x32_i8(              \
              Af[mf], Bf[nf], acc[mf][nf], 0, 0, 0);                        \
  __builtin_amdgcn_s_setprio(0);

#define BODY(slot)                                                          \
  do {                                                                      \
    READ8(slot, 0);                                                         \
    MFMA16();                                                               \
    READ8(slot, 1);                                                         \
    MFMA16();                                                               \
  } while (0)

#define VMWAIT(N) asm volatile("s_waitcnt vmcnt(" #N ")" ::: "memory")

  // K = 4096 B/row = 64 halves of 64B. Half t -> slot t&1.
  STAGE_AB(0, 0);
  for (int tt = 0; tt < 62; tt += 2) {
    STAGE_AB(tt + 1, 1);
    VMWAIT(16);          // retire stage(tt); stage(tt+1) stays in flight
    BODY(0);
    STAGE_AB(tt + 2, 0);
    VMWAIT(16);          // retire stage(tt+1)
    BODY(1);
  }
  STAGE_AB(63, 1);
  VMWAIT(16);            // retire stage(62)
  BODY(0);
  VMWAIT(0);             // retire stage(63)
  BODY(1);

#undef VMWAIT
#undef BODY
#undef MFMA16
#undef READ8
#undef STAGE_AB

  // epilogue (verbatim r13): C/D 32x32 layout col=lane&31,
  // row=(reg&3)+8*(reg>>2)+4*(lane>>5).
  // out = acc * (Delta_m * bf16(s_n)) + bf16(z_n) * xsum_m + bias_n
  const int colv = bn0 + wn * 128 + (lane & 31);
  const int rowb = bm0 + wm * 128 + ((lane >> 5) << 2);
  float sb[4], zb[4], bv[4];
#pragma unroll
  for (int nf = 0; nf < 4; ++nf) {
    sb[nf] = bf16r(scales[colv + nf * 32]);
    zb[nf] = bf16r(zeros[colv + nf * 32]);
    bv[nf] = bias[colv + nf * 32];
  }
#pragma unroll
  for (int mf = 0; mf < 4; ++mf)
#pragma unroll
    for (int reg = 0; reg < 16; ++reg) {
      const int row = rowb + mf * 32 + (reg & 3) + ((reg >> 2) << 3);
      const float dm = delta[row];
      const float xm = xsum[row];
#pragma unroll
      for (int nf = 0; nf < 4; ++nf)
        out[(size_t)row * NDIM + colv + nf * 32] =
            (float)acc[mf][nf][reg] * (dm * sb[nf]) + (zb[nf] * xm + bv[nf]);
    }
}

// ---------------- fallback fused 128x128 bf16 kernel (ws too small) ---------
__global__ __launch_bounds__(256, 3) void gemm_fused_kernel(
    const float* __restrict__ x, const uint32_t* __restrict__ wq,
    const float* __restrict__ scales, const float* __restrict__ zeros,
    const float* __restrict__ bias, float* __restrict__ out) {
  __shared__ __align__(16) char smem[2 * 128 * 64 * 2];
  char* As = smem;
  char* Bs = smem + 16384;

  const int tid  = threadIdx.x;
  const int lane = tid & 63;
  const int wave = tid >> 6;
  const int wm = wave >> 1, wn = wave & 1;

  const int b   = blockIdx.x;
  const int swz = (b & 7) * 344 + (b >> 3);
  const int mt  = swz / 86;
  const int nt  = swz - mt * 86;
  const int bm0 = mt * 128, bn0 = nt * 128;

  f32x4 acc[4][4];
#pragma unroll
  for (int i = 0; i < 4; ++i)
#pragma unroll
    for (int j = 0; j < 4; ++j) acc[i][j] = (f32x4){0.f, 0.f, 0.f, 0.f};

  const int base_a = ((wm * 64 + (lane & 15)) << 7) + ((lane >> 4) << 4);
  const int base_b = ((wn * 64 + (lane & 15)) << 7) + ((lane >> 4) << 4);

  float sv[4], zv[4];
#pragma unroll
  for (int it = 0; it < 4; ++it) {
    int r = bn0 + it * 32 + (tid >> 3);
    sv[it] = bf16r(scales[r]);
    zv[it] = bf16r(zeros[r]);
  }

  for (int kt = 0; kt < KDIM / 64; ++kt) {
    const int k0 = kt * 64;
    __syncthreads();
#pragma unroll
    for (int it = 0; it < 4; ++it) {
      int ch = it * 256 + tid;
      int row = ch >> 3, c8 = ch & 7;
      const float* src = x + (size_t)(bm0 + row) * KDIM + k0 + c8 * 8;
      float4 f0 = *(const float4*)src;
      float4 f1 = *(const float4*)(src + 4);
      u16x8 v;
      v[0] = f2bf(f0.x); v[1] = f2bf(f0.y); v[2] = f2bf(f0.z); v[3] = f2bf(f0.w);
      v[4] = f2bf(f1.x); v[5] = f2bf(f1.y); v[6] = f2bf(f1.z); v[7] = f2bf(f1.w);
      *(u16x8*)(As + row * 128 + c8 * 16) = v;
    }
#pragma unroll
    for (int it = 0; it < 4; ++it) {
      int ch = it * 256 + tid;
      int row = ch >> 3, kp = ch & 7;
      uint32_t w = wq[(size_t)(bn0 + row) * KP + kt * 8 + kp];
      float s = sv[it], z = zv[it];
      u16x8 v;
#pragma unroll
      for (int j = 0; j < 8; ++j) {
        float qf = (float)((w >> (4 * j)) & 0xF);
        float t  = bf16r(qf * s);
        v[j] = f2bf(t + z);
      }
      *(u16x8*)(Bs + row * 128 + kp * 16) = v;
    }
    __syncthreads();
#pragma unroll
    for (int ks = 0; ks < 2; ++ks) {
      bf16x8 af[4], bf[4];
#pragma unroll
      for (int i = 0; i < 4; ++i)
        af[i] = *(const bf16x8*)(As + base_a + i * 2048 + ks * 64);
#pragma unroll
      for (int j = 0; j < 4; ++j)
        bf[j] = *(const bf16x8*)(Bs + base_b + j * 2048 + ks * 64);
#pragma unroll
      for (int i = 0; i < 4; ++i)
#pragma unroll
        for (int j = 0; j < 4; ++j)
          acc[i][j] = __builtin_amdgcn_mfma_f32_16x16x32_bf16(af[i], bf[j],
                                                              acc[i][j], 0, 0, 0);
    }
  }

  const int colbase = bn0 + wn * 64 + (lane & 15);
  const int rowbase = bm0 + wm * 64 + ((lane >> 4) << 2);
  float bv[4];
#pragma unroll
  for (int j = 0; j < 4; ++j) bv[j] = bias[colbase + j * 16];
#pragma unroll
  for (int i = 0; i < 4; ++i) {
#pragma unroll
    for (int j = 0; j < 4; ++j) {
      size_t base = (size_t)(rowbase + i * 16) * NDIM + colbase + j * 16;
#pragma unroll
      for (int r = 0; r < 4; ++r)
        out[base + (size_t)r * NDIM] = acc[i][j][r] + bv[j];
    }
  }
}

extern "C" void kernel_launch(void* const* d_in, const int* in_sizes, int n_in,
                              void* d_out, int out_size, void* d_ws, size_t ws_size,
                              hipStream_t stream) {
  const float*    x      = (const float*)d_in[0];
  const uint32_t* wq     = (const uint32_t*)d_in[1];
  const float*    scales = (const float*)d_in[2];
  const float*    zeros  = (const float*)d_in[3];
  const float*    bias   = (const float*)d_in[4];
  float*          out    = (float*)d_out;

  const size_t offQ = 0;
  const size_t szQ  = (size_t)NDIM * KDIM;           // 45,088,768
  const size_t offX = szQ;
  const size_t szX  = (size_t)MDIM * KDIM;           // 16,777,216
  const size_t offD = offX + szX;                    // 61,865,984
  const size_t offS = offD + MDIM * sizeof(float);
  const size_t need = offS + MDIM * sizeof(float);   // ~61.9 MB

  if (ws_size >= need) {
    char*  Q8    = (char*)d_ws + offQ;
    char*  X8    = (char*)d_ws + offX;
    float* dlt   = (float*)((char*)d_ws + offD);
    float* xsm   = (float*)((char*)d_ws + offS);
    repack_q_kernel<<<(NDIM * KP) / 256, 256, 0, stream>>>(wq, (c8x8*)Q8);
    quant_x_kernel<<<MDIM, 256, 0, stream>>>(x, (c8x16*)X8, dlt, xsm);
    gemm_i8_kernel<<<688, 256, 0, stream>>>(X8, Q8, dlt, xsm, scales, zeros,
                                            bias, out);
  } else {
    gemm_fused_kernel<<<2752, 256, 0, stream>>>(x, wq, scales, zeros, bias, out);
  }
}